// Round 2
// baseline (741.221 us; speedup 1.0000x reference)
//
#include <hip/hip_runtime.h>
#include <stdint.h>

// Problem constants (SRUCell): L=1024, B=32, IN=1024, D=1024
#define L_   1024
#define B_   32
#define IN_  1024
#define D_   1024
#define M_   (L_ * B_)   // 32768  GEMM rows
#define N4_  (4 * D_)    // 4096   GEMM cols
#define K_   IN_         // 1024   GEMM inner

typedef _Float16 f16x8 __attribute__((ext_vector_type(8)));  // 8 fp16 = 4 VGPRs
typedef float    f32x4 __attribute__((ext_vector_type(4)));

#define GLB(p) (const __attribute__((address_space(1))) void*)(p)
#define LDSP(p) (__attribute__((address_space(3))) void*)(p)

__device__ __forceinline__ unsigned short f2h(float f) {
  _Float16 h = (_Float16)f;  // RNE
  return __builtin_bit_cast(unsigned short, h);
}
__device__ __forceinline__ float h2f(unsigned short b) {
  return (float)__builtin_bit_cast(_Float16, b);
}

// ---------------------------------------------------------------- cvt x -> fp16
__global__ void cvt_x(const float* __restrict__ x, unsigned short* __restrict__ xh) {
  int i = (blockIdx.x * 256 + threadIdx.x) * 4;
  float4 v = *(const float4*)(x + i);
  ushort4 o;
  o.x = f2h(v.x); o.y = f2h(v.y); o.z = f2h(v.z); o.w = f2h(v.w);
  *(ushort4*)(xh + i) = o;
}

// ------------------------------------------- transpose W (K_ x N4_) -> Wt fp16 (N4_ x K_)
__global__ void cvt_wt(const float* __restrict__ W, unsigned short* __restrict__ Wt) {
  __shared__ float t[32][33];  // +1 pad breaks bank conflicts
  int tx = threadIdx.x, ty = threadIdx.y;
  int x0 = blockIdx.x * 32, y0 = blockIdx.y * 32;
  t[ty][tx] = W[(size_t)(y0 + ty) * N4_ + x0 + tx];
  __syncthreads();
  // Wt[n][i] = W[i][n], n = x0+ty, i = y0+tx
  Wt[(size_t)(x0 + ty) * K_ + y0 + tx] = f2h(t[tx][ty]);
}

// ---------------------------------------------------------------- GEMM (m97 structure, fp16)
// U[m][n] = sum_k A[m][k] * Bt[n][k];  A: M_ x K_ fp16 row-major, Bt: N4_ x K_ fp16 row-major.
// 128x128 block tile, BK=32, 4 waves (2x2 wave grid), each wave 4x4 MFMA 16x16x32 tiles.
__global__ __launch_bounds__(256) void gemm_u(const unsigned short* __restrict__ A,
                                              const unsigned short* __restrict__ Bt,
                                              unsigned short* __restrict__ U) {
  __shared__ unsigned short As[128 * 32];  // 8 KB, row-major [row][k]
  __shared__ unsigned short Bs[128 * 32];  // 8 KB, row-major [n][k]

  const int tid  = threadIdx.x;
  const int wave = tid >> 6;
  const int lane = tid & 63;
  const int l15  = lane & 15;
  const int quad = lane >> 4;
  const int wm   = wave & 1;   // wave row in 2x2 grid
  const int wn   = wave >> 1;  // wave col
  const int m0   = blockIdx.y * 128;
  const int n0   = blockIdx.x * 128;

  // staging: each global_load_lds issue covers 1024 B = 16 rows x 32 fp16.
  // lane i -> LDS bytes base + i*16  => row i/4, k-offset (i%4)*8 elems.
  const int srow = lane >> 2;
  const int scol = (lane & 3) * 8;

  f32x4 acc[4][4];
#pragma unroll
  for (int i = 0; i < 4; i++)
#pragma unroll
    for (int j = 0; j < 4; j++) acc[i][j] = (f32x4){0.f, 0.f, 0.f, 0.f};

  for (int k0 = 0; k0 < K_; k0 += 32) {
#pragma unroll
    for (int c = 0; c < 2; c++) {
      const int chunk = wave * 2 + c;              // 0..7 (wave-uniform)
      const int row   = chunk * 16 + srow;
      const unsigned short* ga = A  + (size_t)(m0 + row) * K_ + k0 + scol;
      const unsigned short* gb = Bt + (size_t)(n0 + row) * K_ + k0 + scol;
      __builtin_amdgcn_global_load_lds(GLB(ga), LDSP(As + chunk * 512), 16, 0, 0);
      __builtin_amdgcn_global_load_lds(GLB(gb), LDSP(Bs + chunk * 512), 16, 0, 0);
    }
    __syncthreads();  // drains vmcnt for the lds loads

    const f16x8* Af = (const f16x8*)As;  // row r, quad q -> index r*4 + q
    const f16x8* Bf = (const f16x8*)Bs;
    f16x8 a[4], b[4];
#pragma unroll
    for (int mi = 0; mi < 4; mi++) a[mi] = Af[(wm * 64 + mi * 16 + l15) * 4 + quad];
#pragma unroll
    for (int ni = 0; ni < 4; ni++) b[ni] = Bf[(wn * 64 + ni * 16 + l15) * 4 + quad];
#pragma unroll
    for (int mi = 0; mi < 4; mi++)
#pragma unroll
      for (int ni = 0; ni < 4; ni++)
        acc[mi][ni] = __builtin_amdgcn_mfma_f32_16x16x32_f16(a[mi], b[ni], acc[mi][ni], 0, 0, 0);
    __syncthreads();
  }

  // epilogue: C/D layout col = lane&15 (N), row = quad*4 + reg (M); store fp16
#pragma unroll
  for (int mi = 0; mi < 4; mi++) {
#pragma unroll
    for (int ni = 0; ni < 4; ni++) {
      const int row = m0 + wm * 64 + mi * 16 + quad * 4;
      const int col = n0 + wn * 64 + ni * 16 + l15;
#pragma unroll
      for (int i = 0; i < 4; i++)
        U[(size_t)(row + i) * N4_ + col] = f2h(acc[mi][ni][i]);
    }
  }
}

// ---------------------------------------------------------------- sequential scan
// One thread per (b,d) chain; t = b*D_+d. U uint2 index for step l is exactly l*32768 + t.
__global__ void scan_kernel(const unsigned short* __restrict__ U,
                            const float* __restrict__ c0,
                            const float* __restrict__ V,
                            const float* __restrict__ bias,
                            float* __restrict__ out) {
  const int t = blockIdx.x * 64 + threadIdx.x;  // 0..32767
  const int d = t & (D_ - 1);
  float c = c0[t];
  const float vf  = V[d],    vr  = V[D_ + d];
  const float bf_ = bias[d], br_ = bias[D_ + d];
  const uint2* Up = (const uint2*)U;  // 4 fp16 gates per uint2

  constexpr int PF = 8;  // prefetch depth: 8 x 8 B in flight/thread ~ Little's law at HBM latency
  uint2 buf[PF];
#pragma unroll
  for (int j = 0; j < PF; j++) buf[j] = Up[(size_t)j * 32768 + t];

#pragma unroll 1
  for (int l0 = 0; l0 < L_; l0 += PF) {
#pragma unroll
    for (int j = 0; j < PF; j++) {
      uint2 u = buf[j];
      const int lp = l0 + j + PF;
      if (lp < L_) buf[j] = Up[(size_t)lp * 32768 + t];
      const float u0 = h2f((unsigned short)(u.x & 0xffffu));
      const float u1 = h2f((unsigned short)(u.x >> 16));
      const float u2 = h2f((unsigned short)(u.y & 0xffffu));
      const float u3 = h2f((unsigned short)(u.y >> 16));
      const float f = __builtin_amdgcn_rcpf(1.f + __expf(-(u1 + c * vf + bf_)));
      const float r = __builtin_amdgcn_rcpf(1.f + __expf(-(u2 + c * vr + br_)));
      c = u0 + (c - u0) * f;
      const float th = 1.f - 2.f * __builtin_amdgcn_rcpf(1.f + __expf(2.f * c));
      const float h = (th - u3) * r + u3;
      out[(size_t)(l0 + j) * 32768 + t] = h;
    }
  }
  out[(size_t)L_ * 32768 + t] = c;  // c_last appended after h
}

extern "C" void kernel_launch(void* const* d_in, const int* in_sizes, int n_in,
                              void* d_out, int out_size, void* d_ws, size_t ws_size,
                              hipStream_t stream) {
  const float* x    = (const float*)d_in[0];
  const float* c0   = (const float*)d_in[1];
  const float* W    = (const float*)d_in[2];
  const float* V    = (const float*)d_in[3];
  const float* bias = (const float*)d_in[4];
  float* out = (float*)d_out;

  uint8_t* ws = (uint8_t*)d_ws;
  unsigned short* Xh = (unsigned short*)ws;                          // 64 MB fp16 x
  unsigned short* Wt = (unsigned short*)(ws + ((size_t)64 << 20));   // 8 MB fp16 W^T
  unsigned short* U  = (unsigned short*)(ws + ((size_t)72 << 20));   // 256 MB fp16 U
  // total workspace: 328 MB

  cvt_x<<<(M_ * K_) / 1024, 256, 0, stream>>>(x, Xh);
  cvt_wt<<<dim3(N4_ / 32, K_ / 32), dim3(32, 32), 0, stream>>>(W, Wt);
  gemm_u<<<dim3(N4_ / 128, M_ / 128), 256, 0, stream>>>(Xh, Wt, U);
  scan_kernel<<<(B_ * D_) / 64, 64, 0, stream>>>(U, c0, V, bias, out);
}

// Round 3
// 665.974 us; speedup vs baseline: 1.1130x; 1.1130x over previous
//
#include <hip/hip_runtime.h>
#include <stdint.h>

// Problem constants (SRUCell): L=1024, B=32, IN=1024, D=1024
#define L_   1024
#define B_   32
#define IN_  1024
#define D_   1024
#define M_   (L_ * B_)   // 32768  GEMM rows
#define N4_  (4 * D_)    // 4096   GEMM cols
#define K_   IN_         // 1024   GEMM inner

#define L2E      1.4426950408889634f
#define TWO_L2E  2.8853900817779268f

typedef _Float16 f16x8 __attribute__((ext_vector_type(8)));  // 8 fp16 = 4 VGPRs
typedef float    f32x4 __attribute__((ext_vector_type(4)));

#define GLB(p) (const __attribute__((address_space(1))) void*)(p)
#define LDSP(p) (__attribute__((address_space(3))) void*)(p)

__device__ __forceinline__ unsigned short f2h(float f) {
  _Float16 h = (_Float16)f;  // RNE
  return __builtin_bit_cast(unsigned short, h);
}
__device__ __forceinline__ float h2f(unsigned short b) {
  return (float)__builtin_bit_cast(_Float16, b);
}

// ---------------------------------------------------------------- cvt x -> fp16
__global__ void cvt_x(const float* __restrict__ x, unsigned short* __restrict__ xh) {
  int i = (blockIdx.x * 256 + threadIdx.x) * 4;
  float4 v = *(const float4*)(x + i);
  ushort4 o;
  o.x = f2h(v.x); o.y = f2h(v.y); o.z = f2h(v.z); o.w = f2h(v.w);
  *(ushort4*)(xh + i) = o;
}

// ------------------------------------------- transpose W (K_ x N4_) -> Wt fp16 (N4_ x K_)
// Gate columns n&3==1 (f) and n&3==2 (r) are pre-scaled by log2(e) so the scan's
// sigmoids run in exp2 domain with no extra multiply.
__global__ void cvt_wt(const float* __restrict__ W, unsigned short* __restrict__ Wt) {
  __shared__ float t[32][33];  // +1 pad breaks bank conflicts
  int tx = threadIdx.x, ty = threadIdx.y;
  int x0 = blockIdx.x * 32, y0 = blockIdx.y * 32;
  t[ty][tx] = W[(size_t)(y0 + ty) * N4_ + x0 + tx];
  __syncthreads();
  // Wt[n][i] = W[i][n] * scale(n), n = x0+ty, i = y0+tx
  int n = x0 + ty;
  int g = n & 3;
  float s = (g == 1 || g == 2) ? L2E : 1.0f;
  Wt[(size_t)n * K_ + y0 + tx] = f2h(t[tx][ty] * s);
}

// ---------------------------------------------------------------- GEMM (m97 structure, fp16)
// U[m][n] = sum_k A[m][k] * Bt[n][k];  A: M_ x K_ fp16 row-major, Bt: N4_ x K_ fp16 row-major.
// 128x128 block tile, BK=32, 4 waves (2x2 wave grid), each wave 4x4 MFMA 16x16x32 tiles.
__global__ __launch_bounds__(256) void gemm_u(const unsigned short* __restrict__ A,
                                              const unsigned short* __restrict__ Bt,
                                              unsigned short* __restrict__ U) {
  __shared__ unsigned short As[128 * 32];  // 8 KB, row-major [row][k]
  __shared__ unsigned short Bs[128 * 32];  // 8 KB, row-major [n][k]

  const int tid  = threadIdx.x;
  const int wave = tid >> 6;
  const int lane = tid & 63;
  const int l15  = lane & 15;
  const int quad = lane >> 4;
  const int wm   = wave & 1;   // wave row in 2x2 grid
  const int wn   = wave >> 1;  // wave col
  const int m0   = blockIdx.y * 128;
  const int n0   = blockIdx.x * 128;

  // staging: each global_load_lds issue covers 1024 B = 16 rows x 32 fp16.
  // lane i -> LDS bytes base + i*16  => row i/4, k-offset (i%4)*8 elems.
  const int srow = lane >> 2;
  const int scol = (lane & 3) * 8;

  f32x4 acc[4][4];
#pragma unroll
  for (int i = 0; i < 4; i++)
#pragma unroll
    for (int j = 0; j < 4; j++) acc[i][j] = (f32x4){0.f, 0.f, 0.f, 0.f};

  for (int k0 = 0; k0 < K_; k0 += 32) {
#pragma unroll
    for (int c = 0; c < 2; c++) {
      const int chunk = wave * 2 + c;              // 0..7 (wave-uniform)
      const int row   = chunk * 16 + srow;
      const unsigned short* ga = A  + (size_t)(m0 + row) * K_ + k0 + scol;
      const unsigned short* gb = Bt + (size_t)(n0 + row) * K_ + k0 + scol;
      __builtin_amdgcn_global_load_lds(GLB(ga), LDSP(As + chunk * 512), 16, 0, 0);
      __builtin_amdgcn_global_load_lds(GLB(gb), LDSP(Bs + chunk * 512), 16, 0, 0);
    }
    __syncthreads();  // drains vmcnt for the lds loads

    const f16x8* Af = (const f16x8*)As;  // row r, quad q -> index r*4 + q
    const f16x8* Bf = (const f16x8*)Bs;
    f16x8 a[4], b[4];
#pragma unroll
    for (int mi = 0; mi < 4; mi++) a[mi] = Af[(wm * 64 + mi * 16 + l15) * 4 + quad];
#pragma unroll
    for (int ni = 0; ni < 4; ni++) b[ni] = Bf[(wn * 64 + ni * 16 + l15) * 4 + quad];
#pragma unroll
    for (int mi = 0; mi < 4; mi++)
#pragma unroll
      for (int ni = 0; ni < 4; ni++)
        acc[mi][ni] = __builtin_amdgcn_mfma_f32_16x16x32_f16(a[mi], b[ni], acc[mi][ni], 0, 0, 0);
    __syncthreads();
  }

  // epilogue: C/D layout col = lane&15 (N), row = quad*4 + reg (M); store fp16
#pragma unroll
  for (int mi = 0; mi < 4; mi++) {
#pragma unroll
    for (int ni = 0; ni < 4; ni++) {
      const int row = m0 + wm * 64 + mi * 16 + quad * 4;
      const int col = n0 + wn * 64 + ni * 16 + l15;
#pragma unroll
      for (int i = 0; i < 4; i++)
        U[(size_t)(row + i) * N4_ + col] = f2h(acc[mi][ni][i]);
    }
  }
}

// ---------------------------------------------------------------- sequential scan
// One thread per (b,d) chain; t = b*D_+d. U uint2 index for step l is l*32768 + t.
// Gates arrive pre-scaled by log2(e) (u1', u2'), so sigmoid = rcp(1+exp2(-p)).
// PF=16 prefetch: 16 steps x ~70 cyc covers ~1100 cyc >> 900 cyc HBM latency.
__global__ __launch_bounds__(64) void scan_kernel(const unsigned short* __restrict__ U,
                                                  const float* __restrict__ c0,
                                                  const float* __restrict__ V,
                                                  const float* __restrict__ bias,
                                                  float* __restrict__ out) {
  const int t = blockIdx.x * 64 + threadIdx.x;  // 0..32767
  const int d = t & (D_ - 1);
  float c = c0[t];
  const float vfp = V[d] * L2E, vrp = V[D_ + d] * L2E;
  const float bfp = bias[d] * L2E, brp = bias[D_ + d] * L2E;
  const uint2* Up = (const uint2*)U;  // 4 fp16 gates per uint2

  constexpr int PF = 16;
  uint2 buf[PF];
#pragma unroll
  for (int j = 0; j < PF; j++) buf[j] = Up[(size_t)j * 32768 + t];

#define SRU_STEP(u, l)                                                          \
  {                                                                             \
    const float u0 = h2f((unsigned short)((u).x & 0xffffu));                    \
    const float u1 = h2f((unsigned short)((u).x >> 16)); /* pre-scaled */       \
    const float u2 = h2f((unsigned short)((u).y & 0xffffu)); /* pre-scaled */   \
    const float u3 = h2f((unsigned short)((u).y >> 16));                        \
    const float pf = fmaf(c, vfp, u1 + bfp);                                    \
    const float pr = fmaf(c, vrp, u2 + brp);                                    \
    const float f  = __builtin_amdgcn_rcpf(1.f + __builtin_amdgcn_exp2f(-pf));  \
    const float r  = __builtin_amdgcn_rcpf(1.f + __builtin_amdgcn_exp2f(-pr));  \
    c = fmaf(c - u0, f, u0);                                                    \
    const float q  = __builtin_amdgcn_exp2f(c * TWO_L2E);                       \
    const float th = fmaf(-2.f, __builtin_amdgcn_rcpf(1.f + q), 1.f);           \
    const float h  = fmaf(th - u3, r, u3);                                      \
    __builtin_nontemporal_store(h, out + (size_t)(l) * 32768 + t);              \
  }

#pragma unroll 1
  for (int l0 = 0; l0 < L_ - PF; l0 += PF) {
#pragma unroll
    for (int j = 0; j < PF; j++) {
      uint2 u = buf[j];
      buf[j] = Up[(size_t)(l0 + j + PF) * 32768 + t];  // unconditional prefetch
      SRU_STEP(u, l0 + j);
    }
  }
  // tail: last PF steps, no prefetch
#pragma unroll
  for (int j = 0; j < PF; j++) {
    uint2 u = buf[j];
    SRU_STEP(u, L_ - PF + j);
  }
#undef SRU_STEP

  out[(size_t)L_ * 32768 + t] = c;  // c_last appended after h
}

extern "C" void kernel_launch(void* const* d_in, const int* in_sizes, int n_in,
                              void* d_out, int out_size, void* d_ws, size_t ws_size,
                              hipStream_t stream) {
  const float* x    = (const float*)d_in[0];
  const float* c0   = (const float*)d_in[1];
  const float* W    = (const float*)d_in[2];
  const float* V    = (const float*)d_in[3];
  const float* bias = (const float*)d_in[4];
  float* out = (float*)d_out;

  uint8_t* ws = (uint8_t*)d_ws;
  unsigned short* Xh = (unsigned short*)ws;                          // 64 MB fp16 x
  unsigned short* Wt = (unsigned short*)(ws + ((size_t)64 << 20));   // 8 MB fp16 W^T
  unsigned short* U  = (unsigned short*)(ws + ((size_t)72 << 20));   // 256 MB fp16 U
  // total workspace: 328 MB

  cvt_x<<<(M_ * K_) / 1024, 256, 0, stream>>>(x, Xh);
  cvt_wt<<<dim3(N4_ / 32, K_ / 32), dim3(32, 32), 0, stream>>>(W, Wt);
  gemm_u<<<dim3(N4_ / 128, M_ / 128), 256, 0, stream>>>(Xh, Wt, U);
  scan_kernel<<<(B_ * D_) / 64, 64, 0, stream>>>(U, c0, V, bias, out);
}